// Round 7
// baseline (500.013 us; speedup 1.0000x reference)
//
#include <hip/hip_runtime.h>
#include <math.h>

#define BB 256
#define SS 30
#define CC 62
#define LL 169
#define OG 64
#define OH 64
#define KK1 64
#define KK2 32
#define KK3 14
#define T12LEN 95    // 64+32-1
#define FLEN 108     // 64+32+14-2

typedef __attribute__((ext_vector_type(8))) short s16x8;
typedef __attribute__((ext_vector_type(4))) float f32x4;

__device__ __forceinline__ unsigned short f2bf(float f) {
    unsigned u = __float_as_uint(f);
    u += 0x7fffu + ((u >> 16) & 1u);        // RTNE
    return (unsigned short)(u >> 16);
}
__device__ __forceinline__ float bflo(unsigned v) { return __uint_as_float(v << 16); }
__device__ __forceinline__ float bfhi(unsigned v) { return __uint_as_float(v & 0xffff0000u); }

// ---------------- setup kernels ----------------

// T[c1][c0][k'] = pw1_w[c1,c0] * sum_{k2} dw2_w[c1,k2] * dw1_w[c0,k'-k2]
__global__ void k_setup_T(const float* __restrict__ dw1, const float* __restrict__ dw2,
                          const float* __restrict__ pw1, float* __restrict__ Tbuf) {
    int c1 = blockIdx.x / CC, c0 = blockIdx.x % CC;
    int kp = threadIdx.x;
    if (kp >= T12LEN) return;
    int k2lo = max(0, kp - (KK1 - 1));
    int k2hi = min(KK2 - 1, kp);
    float s = 0.f;
    for (int k2 = k2lo; k2 <= k2hi; ++k2)
        s += dw2[c1 * KK2 + k2] * dw1[c0 * KK1 + (kp - k2)];
    Tbuf[(c1 * CC + c0) * T12LEN + kp] = s * pw1[c1 * CC + c0];
}

// g23[c1][k3] = sum_{c2} pw3_w[61,c2] * pw2_w[c2,c1] * dw3_w[c2,k3]   and  beff
__global__ void k_setup_g(const float* __restrict__ pw2, const float* __restrict__ pw3,
                          const float* __restrict__ dw3,
                          const float* __restrict__ dw1b, const float* __restrict__ pw1w,
                          const float* __restrict__ pw1b,
                          const float* __restrict__ dw2, const float* __restrict__ dw2b,
                          const float* __restrict__ pw2b,
                          const float* __restrict__ dw3b, const float* __restrict__ pw3b,
                          float* __restrict__ g23, float* __restrict__ beff) {
    __shared__ float by2[CC], vals[CC];
    int tid = threadIdx.x;
    for (int idx = tid; idx < CC * KK3; idx += blockDim.x) {
        int c1 = idx / KK3, k3 = idx % KK3;
        float s = 0.f;
        for (int c2 = 0; c2 < CC; ++c2)
            s += pw3[61 * CC + c2] * pw2[c2 * CC + c1] * dw3[c2 * KK3 + k3];
        g23[idx] = s;
    }
    if (tid < CC) {
        int c1 = tid;
        float bz1 = pw1b[c1];
        for (int c0 = 0; c0 < CC; ++c0) bz1 += pw1w[c1 * CC + c0] * dw1b[c0];
        float s2 = 0.f;
        for (int k = 0; k < KK2; ++k) s2 += dw2[c1 * KK2 + k];
        by2[c1] = dw2b[c1] + bz1 * s2;
    }
    __syncthreads();
    if (tid < CC) {
        int c2 = tid;
        float bz2 = pw2b[c2];
        for (int c1 = 0; c1 < CC; ++c1) bz2 += pw2[c2 * CC + c1] * by2[c1];
        float s3 = 0.f;
        for (int k = 0; k < KK3; ++k) s3 += dw3[c2 * KK3 + k];
        vals[c2] = pw3[61 * CC + c2] * (dw3b[c2] + bz2 * s3);
    }
    __syncthreads();
    if (tid == 0) {
        float s = pw3b[61];
        for (int c2 = 0; c2 < CC; ++c2) s += vals[c2];
        *beff = s;
    }
}

// Ftb[o][c] = F[c][o] (transposed, zero-padded to 112x64), bf16
__global__ void k_setup_F(const float* __restrict__ Tbuf, const float* __restrict__ g23,
                          unsigned short* __restrict__ Ftb) {
    __shared__ float gl[CC * KK3];
    int c0 = blockIdx.x;                 // 0..63
    for (int i = threadIdx.x; i < CC * KK3; i += blockDim.x) gl[i] = g23[i];
    __syncthreads();
    int o = threadIdx.x;                 // 0..127
    if (o >= 112) return;
    float s = 0.f;
    if (c0 < CC && o < FLEN) {
        int k3hi = min(KK3 - 1, o);
        int k3lo = max(0, o - (T12LEN - 1));
        for (int c1 = 0; c1 < CC; ++c1) {
            const float* Trow = Tbuf + (c1 * CC + c0) * T12LEN;
            for (int k3 = k3lo; k3 <= k3hi; ++k3)
                s += gl[c1 * KK3 + k3] * Trow[o - k3];
        }
    }
    Ftb[o * 64 + c0] = f2bf(s);
}

// Wt[gate][i][f] = W_gate[f][i]  (first-64-col half, transposed)
__global__ void k_setup_Wt(const float* __restrict__ Wr, const float* __restrict__ Wu,
                           const float* __restrict__ Wc, float* __restrict__ Wt) {
    int gate = blockIdx.x;
    const float* W = gate == 0 ? Wr : (gate == 1 ? Wu : Wc);
    for (int idx = threadIdx.x; idx < OG * OH; idx += blockDim.x) {
        int i = idx >> 6, f = idx & 63;
        Wt[gate * OG * OH + idx] = W[f * (OG + OH) + i];
    }
}

// ---------------- main parallel phase: one block per (b,t) ----------------
// Band-only MFMA: P[o][l] tiles with d = nt-mt in [0,4]; epilogue atomicAdds into dacc[copy][j].
__global__ __launch_bounds__(256, 5) void k_main(
        const float* __restrict__ x, const float* __restrict__ adj,
        const unsigned short* __restrict__ Ftb, const float* __restrict__ beff_p,
        const float* __restrict__ gcnw, const float* __restrict__ gcnb,
        const float* __restrict__ Wtr,
        const float* __restrict__ Wrb, const float* __restrict__ br,
        const float* __restrict__ Wub, const float* __restrict__ bu,
        const float* __restrict__ Wcb, const float* __restrict__ bc,
        float* __restrict__ gates) {
    // XOR-swizzled bf16 tile: element [l][c] at byte (l*128 + 2c) ^ ((l&7)<<4)
    __shared__ __align__(16) unsigned short xT[176 * 64];   // 22528 B  (rows l, cols c)
    __shared__ float dacc[4][64];                           // band accumulator copies
    __shared__ float adjt[CC];
    __shared__ float wx[176];
    __shared__ float gpart[4][OG];
    __shared__ float glds[OG];

    int bt = blockIdx.x;            // b*SS + t
    int b = bt / SS, t = bt % SS;
    int tid = threadIdx.x;
    const float* xg = x + (size_t)bt * (CC * LL);
    unsigned* xTu = (unsigned*)xT;

    // zero dacc
    ((float*)dacc)[tid] = 0.f;

    // stage x -> transposed swizzled bf16, packed dword writes: idx = cp*176 + l
    for (int idx = tid; idx < 32 * 176; idx += 256) {
        int cp = idx / 176;
        int l = idx - cp * 176;
        unsigned val = 0;
        if (cp < 31 && l < LL) {
            int c0 = 2 * cp;
            float v0 = xg[c0 * LL + l];
            float v1 = xg[(c0 + 1) * LL + l];
            val = (unsigned)f2bf(v0) | ((unsigned)f2bf(v1) << 16);
        }
        xTu[(l * 32 + cp) ^ ((l & 7) << 2)] = val;
    }
    __syncthreads();

    // ---- MFMA band phase: 35 (mt, d) pairs, d = nt-mt in [0,4] ----
    {
        int lane = tid & 63, wid = tid >> 6;
        int col = lane & 15;
        int rbase4 = lane >> 4;             // 0..3
        int rbase = rbase4 * 4;
        int kb = 16 * rbase4;               // byte offset of k-block in a row
        int xr = (lane & 7) << 4;           // row-XOR (row&7 == lane&7 for 16-aligned row blocks)
        for (int p = wid; p < 35; p += 4) {
            int mt = p / 5, d = p - 5 * mt;
            int nt = mt + d;
            // A-fragments straight from global (L1-resident 14 KB table)
            const unsigned short* ap = Ftb + (mt * 16 + col) * 64 + rbase4 * 8;
            s16x8 a0 = *(const s16x8*)ap;
            s16x8 a1 = *(const s16x8*)(ap + 32);
            // B-fragments from swizzled LDS
            int bbyte = ((nt * 16 + col) * 128 + kb) ^ xr;
            s16x8 b0 = *(const s16x8*)((const char*)xT + bbyte);
            s16x8 b1 = *(const s16x8*)((const char*)xT + bbyte + 64);
            f32x4 z = {0.f, 0.f, 0.f, 0.f};
            z = __builtin_amdgcn_mfma_f32_16x16x32_bf16(a0, b0, z, 0, 0, 0);
            z = __builtin_amdgcn_mfma_f32_16x16x32_bf16(a1, b1, z, 0, 0, 0);
            int jb = 16 * d + col - rbase;
            #pragma unroll
            for (int r = 0; r < 4; ++r) {
                int j = jb - r;
                if ((unsigned)j < 62u) atomicAdd(&dacc[rbase4][j], z[r]);
            }
        }
    }
    __syncthreads();

    // ---- reduce copies + sigmoid ----
    if (tid < CC) {
        float dv = dacc[0][tid] + dacc[1][tid] + dacc[2][tid] + dacc[3][tid];
        float v = dv + *beff_p + adj[61 * CC + tid];
        adjt[tid] = 1.f / (1.f + __expf(-v));
    }
    __syncthreads();

    // ---- wx[l] = sum_j adjt[j] * x[j][l] ----
    if (tid < LL) {
        int l = tid;
        int xorv = (l & 7) << 2;
        float s = 0.f;
        #pragma unroll 31
        for (int m = 0; m < 31; ++m) {
            unsigned v = xTu[(l * 32 + m) ^ xorv];
            s += adjt[2 * m] * bflo(v) + adjt[2 * m + 1] * bfhi(v);
        }
        wx[l] = s;
    }
    __syncthreads();

    // ---- g[f] = gcn_b[f] + sum_l wx[l] * gcn_w[l,f]   (l split over 4 thread groups) ----
    {
        int f = tid & 63, lq = tid >> 6;
        float s = 0.f;
        for (int l = lq; l < LL; l += 4) s += wx[l] * gcnw[l * OG + f];
        gpart[lq][f] = s;
    }
    __syncthreads();
    if (tid < OG)
        glds[tid] = gcnb[tid] + gpart[0][tid] + gpart[1][tid] + gpart[2][tid] + gpart[3][tid];
    __syncthreads();

    // ---- per-gate gf-half pre-activations (+ all biases), transposed weights ----
    if (tid < 3 * OH) {
        int gate = tid >> 6, f = tid & 63;
        const float* Wt = Wtr + gate * OG * OH;
        const float* Wb = gate == 0 ? Wrb : (gate == 1 ? Wub : Wcb);
        const float* bb = gate == 0 ? br  : (gate == 1 ? bu  : bc);
        float s = Wb[f] + bb[f];
        #pragma unroll 4
        for (int i = 0; i < OG; ++i) s += glds[i] * Wt[i * OH + f];
        gates[((size_t)(gate * SS + t) * BB + b) * OH + f] = s;
    }
}

// ---------------- sequential GRU scan over t: one block per batch row ----------------
__global__ __launch_bounds__(256) void k_scan(
        const float* __restrict__ gates,
        const float* __restrict__ Wr, const float* __restrict__ Wu, const float* __restrict__ Wc,
        float* __restrict__ out) {
    __shared__ float hl[OH], rhl[OH];
    int b = blockIdx.x;
    int tid = threadIdx.x;
    int f = tid >> 2, q = tid & 3;
    float wr[16], wu[16], wc[16];
    #pragma unroll
    for (int i = 0; i < 16; ++i) {
        int col = OG + q * 16 + i;
        wr[i] = Wr[f * (OG + OH) + col];
        wu[i] = Wu[f * (OG + OH) + col];
        wc[i] = Wc[f * (OG + OH) + col];
    }
    float h = 0.f;
    if (tid < OH) hl[tid] = 0.f;
    __syncthreads();
    const float* Gr = gates;
    const float* Gu = gates + (size_t)SS * BB * OH;
    const float* Gc = gates + (size_t)2 * SS * BB * OH;
    for (int t = 0; t < SS; ++t) {
        float gr = Gr[((size_t)t * BB + b) * OH + f];
        float gu = Gu[((size_t)t * BB + b) * OH + f];
        float gc = Gc[((size_t)t * BB + b) * OH + f];
        float rv = 0.f, uv = 0.f;
        #pragma unroll
        for (int i = 0; i < 16; ++i) {
            float hv = hl[q * 16 + i];
            rv += wr[i] * hv;
            uv += wu[i] * hv;
        }
        rv += __shfl_xor(rv, 1); rv += __shfl_xor(rv, 2);
        uv += __shfl_xor(uv, 1); uv += __shfl_xor(uv, 2);
        float r = 1.f / (1.f + __expf(-(rv + gr)));
        float u = 1.f / (1.f + __expf(-(uv + gu)));
        if (q == 0) rhl[f] = r * h;
        __syncthreads();
        float cv = 0.f;
        #pragma unroll
        for (int i = 0; i < 16; ++i) cv += wc[i] * rhl[q * 16 + i];
        cv += __shfl_xor(cv, 1); cv += __shfl_xor(cv, 2);
        float cc = tanhf(cv + gc);
        if (q == 0) {
            h = u * h + (1.f - u) * cc;
            hl[f] = h;
        }
        __syncthreads();
    }
    if (q == 0) out[b * OH + f] = h;
}

extern "C" void kernel_launch(void* const* d_in, const int* in_sizes, int n_in,
                              void* d_out, int out_size, void* d_ws, size_t ws_size,
                              hipStream_t stream) {
    const float* x    = (const float*)d_in[0];
    const float* adj  = (const float*)d_in[1];
    const float* dw1w = (const float*)d_in[2];
    const float* dw1b = (const float*)d_in[3];
    const float* pw1w = (const float*)d_in[4];
    const float* pw1b = (const float*)d_in[5];
    const float* dw2w = (const float*)d_in[6];
    const float* dw2b = (const float*)d_in[7];
    const float* pw2w = (const float*)d_in[8];
    const float* pw2b = (const float*)d_in[9];
    const float* dw3w = (const float*)d_in[10];
    const float* dw3b = (const float*)d_in[11];
    const float* pw3w = (const float*)d_in[12];
    const float* pw3b = (const float*)d_in[13];
    const float* gcnw = (const float*)d_in[14];
    const float* gcnb = (const float*)d_in[15];
    const float* Wrw  = (const float*)d_in[16];
    const float* Wrb  = (const float*)d_in[17];
    const float* Wuw  = (const float*)d_in[18];
    const float* Wub  = (const float*)d_in[19];
    const float* Wcw  = (const float*)d_in[20];
    const float* Wcb  = (const float*)d_in[21];
    const float* br   = (const float*)d_in[22];
    const float* bu   = (const float*)d_in[23];
    const float* bc   = (const float*)d_in[24];
    float* out = (float*)d_out;

    // workspace layout (bytes)
    char* ws = (char*)d_ws;
    float* Tbuf           = (float*)(ws + 0);                // 365180 floats
    float* g23            = (float*)(ws + 1460736);          // 868 floats
    float* beff           = (float*)(ws + 1464320);          // 1 float
    unsigned short* Ftb   = (unsigned short*)(ws + 1464576); // 112*64 bf16 (16B aligned)
    float* gates          = (float*)(ws + 1491456);          // 1474560 floats
    float* Wt             = (float*)(ws + 7389696);          // 12288 floats
    (void)ws_size; (void)in_sizes; (void)n_in; (void)out_size;

    k_setup_T<<<CC * CC, 128, 0, stream>>>(dw1w, dw2w, pw1w, Tbuf);
    k_setup_g<<<1, 1024, 0, stream>>>(pw2w, pw3w, dw3w, dw1b, pw1w, pw1b,
                                      dw2w, dw2b, pw2b, dw3b, pw3b, g23, beff);
    k_setup_F<<<64, 128, 0, stream>>>(Tbuf, g23, Ftb);
    k_setup_Wt<<<3, 256, 0, stream>>>(Wrw, Wuw, Wcw, Wt);
    k_main<<<BB * SS, 256, 0, stream>>>(x, adj, Ftb, beff, gcnw, gcnb, Wt,
                                        Wrb, br, Wub, bu, Wcb, bc, gates);
    k_scan<<<BB, 256, 0, stream>>>(gates, Wrw, Wuw, Wcw, out);
}

// Round 8
// 399.192 us; speedup vs baseline: 1.2526x; 1.2526x over previous
//
#include <hip/hip_runtime.h>
#include <math.h>

#define BB 256
#define SS 30
#define CC 62
#define LL 169
#define OG 64
#define OH 64
#define KK1 64
#define KK2 32
#define KK3 14
#define FLEN 108     // 64+32+14-2

typedef __attribute__((ext_vector_type(8))) short s16x8;
typedef __attribute__((ext_vector_type(4))) float f32x4;

__device__ __forceinline__ unsigned short f2bf(float f) {
    unsigned u = __float_as_uint(f);
    u += 0x7fffu + ((u >> 16) & 1u);        // RTNE
    return (unsigned short)(u >> 16);
}
__device__ __forceinline__ float bflo(unsigned v) { return __uint_as_float(v << 16); }
__device__ __forceinline__ float bfhi(unsigned v) { return __uint_as_float(v & 0xffff0000u); }

// ---------------- fused setup: F via m-factorization + WtAll + bias192 + beff ----------------
// F[c0][o] = sum_m B[c0][m] dw1[c0][o-m],  B[c0][m] = sum_c1 pw1[c1,c0] A[c1][m],
// A[c1][m] = sum_{k2+k3=m} dw2[c1,k2] g23[c1,k3],  g23[c1,k3] = sum_c2 pw3[61,c2] pw2[c2,c1] dw3[c2,k3]
__global__ __launch_bounds__(1024) void k_setup(
        const float* __restrict__ dw1, const float* __restrict__ dw1b,
        const float* __restrict__ pw1, const float* __restrict__ pw1b,
        const float* __restrict__ dw2, const float* __restrict__ dw2b,
        const float* __restrict__ pw2, const float* __restrict__ pw2b,
        const float* __restrict__ dw3, const float* __restrict__ dw3b,
        const float* __restrict__ pw3, const float* __restrict__ pw3b,
        const float* __restrict__ Wr, const float* __restrict__ Wrb, const float* __restrict__ br,
        const float* __restrict__ Wu, const float* __restrict__ Wub, const float* __restrict__ bu,
        const float* __restrict__ Wc, const float* __restrict__ Wcb, const float* __restrict__ bc,
        unsigned short* __restrict__ Ftb, float* __restrict__ WtAll,
        float* __restrict__ bias192, float* __restrict__ beff) {
    __shared__ float g23[CC * KK3];     // 868
    __shared__ float Am[CC * 45];       // 2790
    __shared__ float Bm[CC * 45];       // 2790
    __shared__ float by2[CC], vals[CC];
    int tid = threadIdx.x;

    // WtAll[i*192 + q] = W_gate[f][i]; bias192[q] = Wb[f] + b_g[f]
    for (int idx = tid; idx < OG * 192; idx += 1024) {
        int i = idx / 192, q = idx - i * 192;
        int gate = q >> 6, f = q & 63;
        const float* W = gate == 0 ? Wr : (gate == 1 ? Wu : Wc);
        WtAll[idx] = W[f * (OG + OH) + i];
    }
    if (tid < 192) {
        int gate = tid >> 6, f = tid & 63;
        const float* Wb = gate == 0 ? Wrb : (gate == 1 ? Wub : Wcb);
        const float* bb = gate == 0 ? br  : (gate == 1 ? bu  : bc);
        bias192[tid] = Wb[f] + bb[f];
    }

    // g23
    for (int idx = tid; idx < CC * KK3; idx += 1024) {
        int c1 = idx / KK3, k3 = idx - c1 * KK3;
        float s = 0.f;
        for (int c2 = 0; c2 < CC; ++c2)
            s += pw3[61 * CC + c2] * pw2[c2 * CC + c1] * dw3[c2 * KK3 + k3];
        g23[idx] = s;
    }
    // by2 (independent)
    if (tid < CC) {
        int c1 = tid;
        float bz1 = pw1b[c1];
        for (int c0 = 0; c0 < CC; ++c0) bz1 += pw1[c1 * CC + c0] * dw1b[c0];
        float s2 = 0.f;
        for (int k = 0; k < KK2; ++k) s2 += dw2[c1 * KK2 + k];
        by2[c1] = dw2b[c1] + bz1 * s2;
    }
    __syncthreads();

    // vals, Am
    if (tid < CC) {
        int c2 = tid;
        float bz2 = pw2b[c2];
        for (int c1 = 0; c1 < CC; ++c1) bz2 += pw2[c2 * CC + c1] * by2[c1];
        float s3 = 0.f;
        for (int k = 0; k < KK3; ++k) s3 += dw3[c2 * KK3 + k];
        vals[c2] = pw3[61 * CC + c2] * (dw3b[c2] + bz2 * s3);
    }
    for (int idx = tid; idx < CC * 45; idx += 1024) {
        int c1 = idx / 45, m = idx - c1 * 45;
        int k2lo = max(0, m - (KK3 - 1));
        int k2hi = min(KK2 - 1, m);
        float s = 0.f;
        for (int k2 = k2lo; k2 <= k2hi; ++k2)
            s += dw2[c1 * KK2 + k2] * g23[c1 * KK3 + (m - k2)];
        Am[idx] = s;
    }
    __syncthreads();

    if (tid == 0) {
        float s = pw3b[61];
        for (int c2 = 0; c2 < CC; ++c2) s += vals[c2];
        *beff = s;
    }
    // Bm
    for (int idx = tid; idx < CC * 45; idx += 1024) {
        int c0 = idx / 45, m = idx - c0 * 45;
        float s = 0.f;
        for (int c1 = 0; c1 < CC; ++c1) s += pw1[c1 * CC + c0] * Am[c1 * 45 + m];
        Bm[idx] = s;
    }
    __syncthreads();

    // Ftb[o*64 + c0] (zero-padded 112x64)
    for (int idx = tid; idx < 112 * 64; idx += 1024) {
        int o = idx >> 6, c0 = idx & 63;
        float s = 0.f;
        if (c0 < CC && o < FLEN) {
            int mlo = max(0, o - (KK1 - 1));
            int mhi = min(44, o);
            for (int m = mlo; m <= mhi; ++m)
                s += Bm[c0 * 45 + m] * dw1[c0 * KK1 + (o - m)];
        }
        Ftb[idx] = f2bf(s);
    }
}

// ---------------- main: one block per (b,t) -> adjt -> wx (written f32 to global) ----------------
__global__ __launch_bounds__(256, 3) void k_main(
        const float* __restrict__ x, const float* __restrict__ adj,
        const unsigned short* __restrict__ Ftb, const float* __restrict__ beff_p,
        float* __restrict__ wxb) {
    __shared__ __align__(16) unsigned short xT[176 * 64];   // 22528 B, swizzled [l][c]
    __shared__ float dacc[4][64];
    __shared__ float adjt[CC];
    int bt = blockIdx.x;
    int tid = threadIdx.x;
    const uint2* xg2 = (const uint2*)(x + (size_t)bt * (CC * LL));
    unsigned* xTu = (unsigned*)xT;

    // 1) issue ALL staging loads into registers (static indices -> stays in VGPRs)
    uint2 rg[21];
    #pragma unroll
    for (int i = 0; i < 21; ++i) {
        int p = tid + i * 256;
        if (p < 5239) rg[i] = xg2[p];
    }
    // early aux loads (overlap with staging latency)
    float be = *beff_p;
    float arow = 0.f;
    if (tid < CC) arow = adj[61 * CC + tid];
    // A-fragment prefetch for first mt = wid
    int lane = tid & 63, wid = tid >> 6;
    int col = lane & 15, rb4 = lane >> 4;
    const unsigned short* ap0 = Ftb + ((wid * 16 + col) * 64 + rb4 * 8);
    s16x8 pa0 = *(const s16x8*)ap0;
    s16x8 pa1 = *(const s16x8*)(ap0 + 32);
    // zero dacc + xT pads while loads fly
    ((float*)dacc)[tid] = 0.f;
    for (int i = tid; i < 169; i += 256) xTu[(i * 32 + 31) ^ ((i & 7) << 2)] = 0;
    for (int i = tid; i < 224; i += 256) {
        int r = 169 + (i >> 5), d = i & 31;
        xTu[(r * 32 + d) ^ ((r & 7) << 2)] = 0;
    }
    // 2) convert + transposed swizzled LDS writes
    #pragma unroll
    for (int i = 0; i < 21; ++i) {
        int p = tid + i * 256;
        if (p < 5239) {
            uint2 v = rg[i];
            int i0 = 2 * p;
            int c = i0 / LL;
            int l = i0 - c * LL;
            *(unsigned short*)((char*)xT + ((l * 128 + 2 * c) ^ ((l & 7) << 4))) =
                f2bf(__uint_as_float(v.x));
            int l2 = l + 1, c2 = c;
            if (l2 == LL) { l2 = 0; c2 = c + 1; }
            *(unsigned short*)((char*)xT + ((l2 * 128 + 2 * c2) ^ ((l2 & 7) << 4))) =
                f2bf(__uint_as_float(v.y));
        }
    }
    __syncthreads();

    // 3) MFMA band: wave wid handles mt in {wid, wid+4}; zacc[d] accumulates across mt
    f32x4 zacc[5];
    #pragma unroll
    for (int d = 0; d < 5; ++d) zacc[d] = (f32x4){0.f, 0.f, 0.f, 0.f};
    int kb = rb4 * 16;
    int xr = (lane & 7) << 4;
    #pragma unroll
    for (int h = 0; h < 2; ++h) {
        int mt = wid + 4 * h;
        if (mt < 7) {
            s16x8 a0, a1;
            if (h == 0) { a0 = pa0; a1 = pa1; }
            else {
                const unsigned short* ap = Ftb + ((mt * 16 + col) * 64 + rb4 * 8);
                a0 = *(const s16x8*)ap;
                a1 = *(const s16x8*)(ap + 32);
            }
            #pragma unroll
            for (int d = 0; d < 5; ++d) {
                int nt = mt + d;
                int bbyte = ((nt * 16 + col) * 128 + kb) ^ xr;
                s16x8 b0 = *(const s16x8*)((const char*)xT + bbyte);
                s16x8 b1 = *(const s16x8*)((const char*)xT + bbyte + 64);
                zacc[d] = __builtin_amdgcn_mfma_f32_16x16x32_bf16(a0, b0, zacc[d], 0, 0, 0);
                zacc[d] = __builtin_amdgcn_mfma_f32_16x16x32_bf16(a1, b1, zacc[d], 0, 0, 0);
            }
        }
    }
    // epilogue scatter: j depends only on (d, r, lane)
    int jc = col - rb4 * 4;
    #pragma unroll
    for (int d = 0; d < 5; ++d) {
        #pragma unroll
        for (int r = 0; r < 4; ++r) {
            int j = 16 * d + jc - r;
            if ((unsigned)j < 62u) atomicAdd(&dacc[rb4][j], zacc[d][r]);
        }
    }
    __syncthreads();

    // 4) sigmoid
    if (tid < CC) {
        float dv = dacc[0][tid] + dacc[1][tid] + dacc[2][tid] + dacc[3][tid];
        adjt[tid] = 1.f / (1.f + __expf(-(dv + be + arow)));
    }
    __syncthreads();

    // 5) wx -> global f32 (rows padded to 176)
    if (tid < 176) {
        float s = 0.f;
        if (tid < LL) {
            int xorv = (tid & 7) << 2;
            #pragma unroll
            for (int m = 0; m < 31; ++m) {
                unsigned v = xTu[(tid * 32 + m) ^ xorv];
                s += adjt[2 * m] * bflo(v) + adjt[2 * m + 1] * bfhi(v);
            }
        }
        wxb[(size_t)bt * 176 + tid] = s;
    }
}

// ---------------- G = wx @ gcn_w + gcn_b : one thread per (bt, f) ----------------
__global__ __launch_bounds__(256) void k_g(
        const float* __restrict__ wxb, const float* __restrict__ gcnw,
        const float* __restrict__ gcnb, float* __restrict__ G) {
    int gid = blockIdx.x * 256 + threadIdx.x;
    int bt = gid >> 6, f = gid & 63;
    const float* wr = wxb + (size_t)bt * 176;
    float s = gcnb[f];
    #pragma unroll 13
    for (int l = 0; l < LL; ++l) s += wr[l] * gcnw[l * OG + f];
    G[gid] = s;
}

// ---------------- gates = G @ W^T + biases : one thread per (bt, gate*64+f) ----------------
__global__ __launch_bounds__(256) void k_gates(
        const float* __restrict__ G, const float* __restrict__ WtAll,
        const float* __restrict__ bias192, float* __restrict__ gates) {
    int gid = blockIdx.x * 256 + threadIdx.x;
    int bt = gid / 192, q = gid - bt * 192;
    const float* gr = G + (size_t)bt * 64;
    float s = bias192[q];
    #pragma unroll 16
    for (int i = 0; i < OG; ++i) s += gr[i] * WtAll[i * 192 + q];
    int gate = q >> 6, f = q & 63;
    int b = bt / SS, t = bt - b * SS;
    gates[((size_t)(gate * SS + t) * BB + b) * OH + f] = s;
}

// ---------------- sequential GRU scan over t: one block per batch row ----------------
__global__ __launch_bounds__(256) void k_scan(
        const float* __restrict__ gates,
        const float* __restrict__ Wr, const float* __restrict__ Wu, const float* __restrict__ Wc,
        float* __restrict__ out) {
    __shared__ float hl[OH], rhl[OH];
    int b = blockIdx.x;
    int tid = threadIdx.x;
    int f = tid >> 2, q = tid & 3;
    float wr[16], wu[16], wc[16];
    #pragma unroll
    for (int i = 0; i < 16; ++i) {
        int col = OG + q * 16 + i;
        wr[i] = Wr[f * (OG + OH) + col];
        wu[i] = Wu[f * (OG + OH) + col];
        wc[i] = Wc[f * (OG + OH) + col];
    }
    float h = 0.f;
    if (tid < OH) hl[tid] = 0.f;
    __syncthreads();
    const float* Gr = gates;
    const float* Gu = gates + (size_t)SS * BB * OH;
    const float* Gc = gates + (size_t)2 * SS * BB * OH;
    for (int t = 0; t < SS; ++t) {
        float gr = Gr[((size_t)t * BB + b) * OH + f];
        float gu = Gu[((size_t)t * BB + b) * OH + f];
        float gc = Gc[((size_t)t * BB + b) * OH + f];
        float rv = 0.f, uv = 0.f;
        #pragma unroll
        for (int i = 0; i < 16; ++i) {
            float hv = hl[q * 16 + i];
            rv += wr[i] * hv;
            uv += wu[i] * hv;
        }
        rv += __shfl_xor(rv, 1); rv += __shfl_xor(rv, 2);
        uv += __shfl_xor(uv, 1); uv += __shfl_xor(uv, 2);
        float r = 1.f / (1.f + __expf(-(rv + gr)));
        float u = 1.f / (1.f + __expf(-(uv + gu)));
        if (q == 0) rhl[f] = r * h;
        __syncthreads();
        float cv = 0.f;
        #pragma unroll
        for (int i = 0; i < 16; ++i) cv += wc[i] * rhl[q * 16 + i];
        cv += __shfl_xor(cv, 1); cv += __shfl_xor(cv, 2);
        float cc = tanhf(cv + gc);
        if (q == 0) {
            h = u * h + (1.f - u) * cc;
            hl[f] = h;
        }
        __syncthreads();
    }
    if (q == 0) out[b * OH + f] = h;
}

extern "C" void kernel_launch(void* const* d_in, const int* in_sizes, int n_in,
                              void* d_out, int out_size, void* d_ws, size_t ws_size,
                              hipStream_t stream) {
    const float* x    = (const float*)d_in[0];
    const float* adj  = (const float*)d_in[1];
    const float* dw1w = (const float*)d_in[2];
    const float* dw1b = (const float*)d_in[3];
    const float* pw1w = (const float*)d_in[4];
    const float* pw1b = (const float*)d_in[5];
    const float* dw2w = (const float*)d_in[6];
    const float* dw2b = (const float*)d_in[7];
    const float* pw2w = (const float*)d_in[8];
    const float* pw2b = (const float*)d_in[9];
    const float* dw3w = (const float*)d_in[10];
    const float* dw3b = (const float*)d_in[11];
    const float* pw3w = (const float*)d_in[12];
    const float* pw3b = (const float*)d_in[13];
    const float* gcnw = (const float*)d_in[14];
    const float* gcnb = (const float*)d_in[15];
    const float* Wrw  = (const float*)d_in[16];
    const float* Wrb  = (const float*)d_in[17];
    const float* Wuw  = (const float*)d_in[18];
    const float* Wub  = (const float*)d_in[19];
    const float* Wcw  = (const float*)d_in[20];
    const float* Wcb  = (const float*)d_in[21];
    const float* br   = (const float*)d_in[22];
    const float* bu   = (const float*)d_in[23];
    const float* bc   = (const float*)d_in[24];
    float* out = (float*)d_out;

    // workspace layout (bytes), total ~7.93 MB; wxb and gates share a region (disjoint in time)
    char* ws = (char*)d_ws;
    unsigned short* Ftb = (unsigned short*)(ws + 0);        // 112*64 bf16 = 14336 B
    float* WtAll        = (float*)(ws + 14336);             // 64*192 f32 = 49152 B
    float* bias192      = (float*)(ws + 63488);             // 768 B
    float* beff         = (float*)(ws + 64256);             // 4 B (pad to 64512)
    float* G            = (float*)(ws + 64512);             // 7680*64 f32 = 1966080 B
    float* wxb          = (float*)(ws + 2030592);           // 7680*176 f32 = 5406720 B
    float* gates        = (float*)(ws + 2030592);           // 3*30*256*64 f32 = 5898240 B (reuses wxb)
    (void)ws_size; (void)in_sizes; (void)n_in; (void)out_size;

    k_setup<<<1, 1024, 0, stream>>>(dw1w, dw1b, pw1w, pw1b, dw2w, dw2b, pw2w, pw2b,
                                    dw3w, dw3b, pw3w, pw3b,
                                    Wrw, Wrb, br, Wuw, Wub, bu, Wcw, Wcb, bc,
                                    Ftb, WtAll, bias192, beff);
    k_main<<<BB * SS, 256, 0, stream>>>(x, adj, Ftb, beff, wxb);
    k_g<<<(BB * SS * OG) / 256, 256, 0, stream>>>(wxb, gcnw, gcnb, G);
    k_gates<<<(BB * SS * 192) / 256, 256, 0, stream>>>(G, WtAll, bias192, gates);
    k_scan<<<BB, 256, 0, stream>>>(gates, Wrw, Wuw, Wcw, out);
}

// Round 9
// 328.045 us; speedup vs baseline: 1.5242x; 1.2169x over previous
//
#include <hip/hip_runtime.h>
#include <math.h>

#define BB 256
#define SS 30
#define CC 62
#define LL 169
#define OG 64
#define OH 64
#define KK1 64
#define KK2 32
#define KK3 14
#define FLEN 108     // 64+32+14-2

typedef __attribute__((ext_vector_type(8))) short s16x8;
typedef __attribute__((ext_vector_type(4))) float f32x4;

__device__ __forceinline__ unsigned short f2bf(float f) {
    unsigned u = __float_as_uint(f);
    u += 0x7fffu + ((u >> 16) & 1u);        // RTNE
    return (unsigned short)(u >> 16);
}
__device__ __forceinline__ float bflo(unsigned v) { return __uint_as_float(v << 16); }
__device__ __forceinline__ float bfhi(unsigned v) { return __uint_as_float(v & 0xffff0000u); }

// ---------------- setup stage 1 (1 block): weights prep + Bm ----------------
// F[c0][o] = sum_m Bm[c0][m] dw1[c0][o-m]; Bm = pw1^T @ Am; Am[c1][m] = conv(dw2[c1], g23[c1]);
// g23[c1][k3] = sum_c2 pw3[61,c2] pw2[c2,c1] dw3[c2,k3]
__global__ __launch_bounds__(1024) void k_setup1(
        const float* __restrict__ dw1, const float* __restrict__ dw1b,
        const float* __restrict__ pw1, const float* __restrict__ pw1b,
        const float* __restrict__ dw2, const float* __restrict__ dw2b,
        const float* __restrict__ pw2, const float* __restrict__ pw2b,
        const float* __restrict__ dw3, const float* __restrict__ dw3b,
        const float* __restrict__ pw3, const float* __restrict__ pw3b,
        const float* __restrict__ Wr, const float* __restrict__ Wrb, const float* __restrict__ br,
        const float* __restrict__ Wu, const float* __restrict__ Wub, const float* __restrict__ bu,
        const float* __restrict__ Wc, const float* __restrict__ Wcb, const float* __restrict__ bc,
        float* __restrict__ Bmg, float* __restrict__ WtAll,
        float* __restrict__ bias192, float* __restrict__ beff) {
    __shared__ float g23[CC * KK3];     // 868
    __shared__ float Am[CC * 45];       // 2790
    __shared__ float by2[CC], vals[CC];
    int tid = threadIdx.x;

    // WtAll[i*192 + q] = W_gate[f][i]; bias192[q] = Wb[f] + b_g[f]
    for (int idx = tid; idx < OG * 192; idx += 1024) {
        int i = idx / 192, q = idx - i * 192;
        int gate = q >> 6, f = q & 63;
        const float* W = gate == 0 ? Wr : (gate == 1 ? Wu : Wc);
        WtAll[idx] = W[f * (OG + OH) + i];
    }
    if (tid < 192) {
        int gate = tid >> 6, f = tid & 63;
        const float* Wb = gate == 0 ? Wrb : (gate == 1 ? Wub : Wcb);
        const float* bb = gate == 0 ? br  : (gate == 1 ? bu  : bc);
        bias192[tid] = Wb[f] + bb[f];
    }

    // g23
    for (int idx = tid; idx < CC * KK3; idx += 1024) {
        int c1 = idx / KK3, k3 = idx - c1 * KK3;
        float s = 0.f;
        for (int c2 = 0; c2 < CC; ++c2)
            s += pw3[61 * CC + c2] * pw2[c2 * CC + c1] * dw3[c2 * KK3 + k3];
        g23[idx] = s;
    }
    // by2 (independent)
    if (tid < CC) {
        int c1 = tid;
        float bz1 = pw1b[c1];
        for (int c0 = 0; c0 < CC; ++c0) bz1 += pw1[c1 * CC + c0] * dw1b[c0];
        float s2 = 0.f;
        for (int k = 0; k < KK2; ++k) s2 += dw2[c1 * KK2 + k];
        by2[c1] = dw2b[c1] + bz1 * s2;
    }
    __syncthreads();

    // vals, Am
    if (tid < CC) {
        int c2 = tid;
        float bz2 = pw2b[c2];
        for (int c1 = 0; c1 < CC; ++c1) bz2 += pw2[c2 * CC + c1] * by2[c1];
        float s3 = 0.f;
        for (int k = 0; k < KK3; ++k) s3 += dw3[c2 * KK3 + k];
        vals[c2] = pw3[61 * CC + c2] * (dw3b[c2] + bz2 * s3);
    }
    for (int idx = tid; idx < CC * 45; idx += 1024) {
        int c1 = idx / 45, m = idx - c1 * 45;
        int k2lo = max(0, m - (KK3 - 1));
        int k2hi = min(KK2 - 1, m);
        float s = 0.f;
        for (int k2 = k2lo; k2 <= k2hi; ++k2)
            s += dw2[c1 * KK2 + k2] * g23[c1 * KK3 + (m - k2)];
        Am[idx] = s;
    }
    __syncthreads();

    if (tid == 0) {
        float s = pw3b[61];
        for (int c2 = 0; c2 < CC; ++c2) s += vals[c2];
        *beff = s;
    }
    // Bm -> global
    for (int idx = tid; idx < CC * 45; idx += 1024) {
        int c0 = idx / 45, m = idx - c0 * 45;
        float s = 0.f;
        for (int c1 = 0; c1 < CC; ++c1) s += pw1[c1 * CC + c0] * Am[c1 * 45 + m];
        Bmg[idx] = s;
    }
}

// ---------------- setup stage 2 (64 blocks): Ftb[o][c0] ----------------
__global__ __launch_bounds__(128) void k_setupF(
        const float* __restrict__ Bmg, const float* __restrict__ dw1,
        unsigned short* __restrict__ Ftb) {
    __shared__ float Bl[45];
    int c0 = blockIdx.x;
    int o = threadIdx.x;
    if (c0 < CC && o < 45) Bl[o] = Bmg[c0 * 45 + o];
    __syncthreads();
    if (o >= 112) return;
    float s = 0.f;
    if (c0 < CC && o < FLEN) {
        int mlo = max(0, o - (KK1 - 1));
        int mhi = min(44, o);
        for (int m = mlo; m <= mhi; ++m)
            s += Bl[m] * dw1[c0 * KK1 + (o - m)];
    }
    Ftb[o * 64 + c0] = f2bf(s);
}

// ---------------- main: one block per (b,t) -> adjt -> wx (written f32 to global) ----------------
__global__ __launch_bounds__(256, 2) void k_main(
        const float* __restrict__ x, const float* __restrict__ adj,
        const unsigned short* __restrict__ Ftb, const float* __restrict__ beff_p,
        float* __restrict__ wxb) {
    __shared__ __align__(16) unsigned short xT[176 * 64];   // 22528 B, swizzled [l][c]
    __shared__ float dacc[4][64];
    __shared__ float adjt[CC];
    int bt = blockIdx.x;
    int tid = threadIdx.x;
    const uint2* xg2 = (const uint2*)(x + (size_t)bt * (CC * LL));
    unsigned* xTu = (unsigned*)xT;

    // 1) issue ALL 21 staging loads (clamped tail; duplicates benign), keep in flight
    uint2 rg[21];
    #pragma unroll
    for (int i = 0; i < 21; ++i) {
        int p = tid + i * 256;
        if (p > 5238) p = 5238;
        rg[i] = xg2[p];
    }
    // aux loads (overlap with staging latency)
    float be = *beff_p;
    float arow = 0.f;
    if (tid < CC) arow = adj[61 * CC + tid];
    int lane = tid & 63, wid = tid >> 6;
    int col = lane & 15, rb4 = lane >> 4;
    const unsigned short* ap0 = Ftb + ((wid * 16 + col) * 64 + rb4 * 8);
    s16x8 pa0 = *(const s16x8*)ap0;
    s16x8 pa1 = *(const s16x8*)(ap0 + 32);
    __builtin_amdgcn_sched_barrier(0);   // pin: all loads issued before anything below

    // zero dacc + xT pads while loads fly
    ((float*)dacc)[tid] = 0.f;
    for (int i = tid; i < 169; i += 256) xTu[(i * 32 + 31) ^ ((i & 7) << 2)] = 0;
    for (int i = tid; i < 224; i += 256) {
        int r = 169 + (i >> 5), d = i & 31;
        xTu[(r * 32 + d) ^ ((r & 7) << 2)] = 0;
    }
    // 2) convert + transposed swizzled LDS writes (vmcnt-counted per element)
    #pragma unroll
    for (int i = 0; i < 21; ++i) {
        int p = tid + i * 256;
        if (p > 5238) p = 5238;
        uint2 v = rg[i];
        int i0 = 2 * p;
        int c = i0 / LL;
        int l = i0 - c * LL;
        *(unsigned short*)((char*)xT + ((l * 128 + 2 * c) ^ ((l & 7) << 4))) =
            f2bf(__uint_as_float(v.x));
        int l2 = l + 1, c2 = c;
        if (l2 == LL) { l2 = 0; c2 = c + 1; }
        *(unsigned short*)((char*)xT + ((l2 * 128 + 2 * c2) ^ ((l2 & 7) << 4))) =
            f2bf(__uint_as_float(v.y));
    }
    __syncthreads();

    // 3) MFMA band: wave wid handles mt in {wid, wid+4}; zacc[d] accumulates across mt
    f32x4 zacc[5];
    #pragma unroll
    for (int d = 0; d < 5; ++d) zacc[d] = (f32x4){0.f, 0.f, 0.f, 0.f};
    int kb = rb4 * 16;
    int xr = (lane & 7) << 4;
    #pragma unroll
    for (int h = 0; h < 2; ++h) {
        int mt = wid + 4 * h;
        if (mt < 7) {
            s16x8 a0, a1;
            if (h == 0) { a0 = pa0; a1 = pa1; }
            else {
                const unsigned short* ap = Ftb + ((mt * 16 + col) * 64 + rb4 * 8);
                a0 = *(const s16x8*)ap;
                a1 = *(const s16x8*)(ap + 32);
            }
            #pragma unroll
            for (int d = 0; d < 5; ++d) {
                int nt = mt + d;
                int bbyte = ((nt * 16 + col) * 128 + kb) ^ xr;
                s16x8 b0 = *(const s16x8*)((const char*)xT + bbyte);
                s16x8 b1 = *(const s16x8*)((const char*)xT + bbyte + 64);
                zacc[d] = __builtin_amdgcn_mfma_f32_16x16x32_bf16(a0, b0, zacc[d], 0, 0, 0);
                zacc[d] = __builtin_amdgcn_mfma_f32_16x16x32_bf16(a1, b1, zacc[d], 0, 0, 0);
            }
        }
    }
    // epilogue scatter: j depends only on (d, r, lane)
    int jc = col - rb4 * 4;
    #pragma unroll
    for (int d = 0; d < 5; ++d) {
        #pragma unroll
        for (int r = 0; r < 4; ++r) {
            int j = 16 * d + jc - r;
            if ((unsigned)j < 62u) atomicAdd(&dacc[rb4][j], zacc[d][r]);
        }
    }
    __syncthreads();

    // 4) sigmoid
    if (tid < CC) {
        float dv = dacc[0][tid] + dacc[1][tid] + dacc[2][tid] + dacc[3][tid];
        adjt[tid] = 1.f / (1.f + __expf(-(dv + be + arow)));
    }
    __syncthreads();

    // 5) wx -> global f32 (rows padded to 176)
    if (tid < 176) {
        float s = 0.f;
        if (tid < LL) {
            int xorv = (tid & 7) << 2;
            #pragma unroll
            for (int m = 0; m < 31; ++m) {
                unsigned v = xTu[(tid * 32 + m) ^ xorv];
                s += adjt[2 * m] * bflo(v) + adjt[2 * m + 1] * bfhi(v);
            }
        }
        wxb[(size_t)bt * 176 + tid] = s;
    }
}

// ---------------- G = wx @ gcn_w + gcn_b : one thread per (bt, f) ----------------
__global__ __launch_bounds__(256) void k_g(
        const float* __restrict__ wxb, const float* __restrict__ gcnw,
        const float* __restrict__ gcnb, float* __restrict__ G) {
    int gid = blockIdx.x * 256 + threadIdx.x;
    int bt = gid >> 6, f = gid & 63;
    const float* wr = wxb + (size_t)bt * 176;
    float s = gcnb[f];
    #pragma unroll 13
    for (int l = 0; l < LL; ++l) s += wr[l] * gcnw[l * OG + f];
    G[gid] = s;
}

// ---------------- gates[bt][192] = G @ W^T + biases (coalesced) ----------------
__global__ __launch_bounds__(256) void k_gates(
        const float* __restrict__ G, const float* __restrict__ WtAll,
        const float* __restrict__ bias192, float* __restrict__ gates) {
    int gid = blockIdx.x * 256 + threadIdx.x;
    int bt = gid / 192, q = gid - bt * 192;
    const float* gr = G + (size_t)bt * 64;
    float s = bias192[q];
    #pragma unroll 16
    for (int i = 0; i < OG; ++i) s += gr[i] * WtAll[i * 192 + q];
    gates[gid] = s;
}

// ---------------- sequential GRU scan over t: one block per batch row ----------------
__global__ __launch_bounds__(256) void k_scan(
        const float* __restrict__ gates,
        const float* __restrict__ Wr, const float* __restrict__ Wu, const float* __restrict__ Wc,
        float* __restrict__ out) {
    __shared__ float hl[OH], rhl[OH];
    int b = blockIdx.x;
    int tid = threadIdx.x;
    int f = tid >> 2, q = tid & 3;
    float wr[16], wu[16], wc[16];
    #pragma unroll
    for (int i = 0; i < 16; ++i) {
        int col = OG + q * 16 + i;
        wr[i] = Wr[f * (OG + OH) + col];
        wu[i] = Wu[f * (OG + OH) + col];
        wc[i] = Wc[f * (OG + OH) + col];
    }
    float h = 0.f;
    if (tid < OH) hl[tid] = 0.f;
    __syncthreads();
    for (int t = 0; t < SS; ++t) {
        const float* gp = gates + ((size_t)b * SS + t) * 192;
        float gr = gp[f];
        float gu = gp[64 + f];
        float gc = gp[128 + f];
        float rv = 0.f, uv = 0.f;
        #pragma unroll
        for (int i = 0; i < 16; ++i) {
            float hv = hl[q * 16 + i];
            rv += wr[i] * hv;
            uv += wu[i] * hv;
        }
        rv += __shfl_xor(rv, 1); rv += __shfl_xor(rv, 2);
        uv += __shfl_xor(uv, 1); uv += __shfl_xor(uv, 2);
        float r = 1.f / (1.f + __expf(-(rv + gr)));
        float u = 1.f / (1.f + __expf(-(uv + gu)));
        if (q == 0) rhl[f] = r * h;
        __syncthreads();
        float cv = 0.f;
        #pragma unroll
        for (int i = 0; i < 16; ++i) cv += wc[i] * rhl[q * 16 + i];
        cv += __shfl_xor(cv, 1); cv += __shfl_xor(cv, 2);
        float cc = tanhf(cv + gc);
        if (q == 0) {
            h = u * h + (1.f - u) * cc;
            hl[f] = h;
        }
        __syncthreads();
    }
    if (q == 0) out[b * OH + f] = h;
}

extern "C" void kernel_launch(void* const* d_in, const int* in_sizes, int n_in,
                              void* d_out, int out_size, void* d_ws, size_t ws_size,
                              hipStream_t stream) {
    const float* x    = (const float*)d_in[0];
    const float* adj  = (const float*)d_in[1];
    const float* dw1w = (const float*)d_in[2];
    const float* dw1b = (const float*)d_in[3];
    const float* pw1w = (const float*)d_in[4];
    const float* pw1b = (const float*)d_in[5];
    const float* dw2w = (const float*)d_in[6];
    const float* dw2b = (const float*)d_in[7];
    const float* pw2w = (const float*)d_in[8];
    const float* pw2b = (const float*)d_in[9];
    const float* dw3w = (const float*)d_in[10];
    const float* dw3b = (const float*)d_in[11];
    const float* pw3w = (const float*)d_in[12];
    const float* pw3b = (const float*)d_in[13];
    const float* gcnw = (const float*)d_in[14];
    const float* gcnb = (const float*)d_in[15];
    const float* Wrw  = (const float*)d_in[16];
    const float* Wrb  = (const float*)d_in[17];
    const float* Wuw  = (const float*)d_in[18];
    const float* Wub  = (const float*)d_in[19];
    const float* Wcw  = (const float*)d_in[20];
    const float* Wcb  = (const float*)d_in[21];
    const float* br   = (const float*)d_in[22];
    const float* bu   = (const float*)d_in[23];
    const float* bc   = (const float*)d_in[24];
    float* out = (float*)d_out;

    // workspace layout (bytes); gates reuses the wxb region (disjoint in time)
    char* ws = (char*)d_ws;
    unsigned short* Ftb = (unsigned short*)(ws + 0);        // 14336 B
    float* WtAll        = (float*)(ws + 14336);             // 49152 B
    float* bias192      = (float*)(ws + 63488);             // 768 B
    float* beff         = (float*)(ws + 64256);             // 4 B
    float* Bmg          = (float*)(ws + 64320);             // 62*45*4 = 11160 B
    float* G            = (float*)(ws + 76800);             // 7680*64*4 = 1966080 B
    float* wxb          = (float*)(ws + 2042880);           // 7680*176*4 = 5406720 B
    float* gates        = (float*)(ws + 2042880);           // 7680*192*4 = 5898240 B (reuses wxb)
    (void)ws_size; (void)in_sizes; (void)n_in; (void)out_size;

    k_setup1<<<1, 1024, 0, stream>>>(dw1w, dw1b, pw1w, pw1b, dw2w, dw2b, pw2w, pw2b,
                                     dw3w, dw3b, pw3w, pw3b,
                                     Wrw, Wrb, br, Wuw, Wub, bu, Wcw, Wcb, bc,
                                     Bmg, WtAll, bias192, beff);
    k_setupF<<<64, 128, 0, stream>>>(Bmg, dw1w, Ftb);
    k_main<<<BB * SS, 256, 0, stream>>>(x, adj, Ftb, beff, wxb);
    k_g<<<(BB * SS * OG) / 256, 256, 0, stream>>>(wxb, gcnw, gcnb, G);
    k_gates<<<(BB * SS * 192) / 256, 256, 0, stream>>>(G, WtAll, bias192, gates);
    k_scan<<<BB, 256, 0, stream>>>(gates, Wrw, Wuw, Wcw, out);
}